// Round 10
// baseline (90.252 us; speedup 1.0000x reference)
//
#include <hip/hip_runtime.h>
#include <hip/hip_fp16.h>

typedef __attribute__((ext_vector_type(8))) _Float16 half8;
typedef __attribute__((ext_vector_type(4))) float f32x4;

namespace {
constexpr int B_G = 131072;     // graphs
constexpr int P   = 22;
constexpr int F   = 14;
constexpr int NF  = 308;        // P*F
constexpr long long N_NODES = (long long)B_G * P;

constexpr int G    = 32;        // graphs per block (halved: LDS -> 26KB -> 5-6 blocks/CU)
constexpr int NBLK = B_G / G;   // 4096

constexpr int KS1 = 10;         // ceil(308/32)
constexpr int KS2 = 8;          // 256/32
constexpr int KS3 = 4;          // 128/32
constexpr int JT1 = 16;         // 256/16
constexpr int JT2 = 8;          // 128/16
constexpr int JT3 = 2;          // 22 -> pad 32

// d_ws byte offsets; single-term fp16 weights, MFMA B-fragment order (1KB/fragment)
constexpr int W1F = 0;
constexpr int W2F = W1F + KS1 * JT1 * 1024;   // 163840
constexpr int W3F = W2F + KS2 * JT2 * 1024;   // 229376
constexpr int CVT_DWORDS = (KS1*JT1 + KS2*JT2 + KS3*JT3) * 256;  // 59392
}

__device__ __forceinline__ unsigned short f2h(float v) {
    __half h = __float2half(v);
    return *reinterpret_cast<unsigned short*>(&h);
}

// ---- one-time weight conversion: fp32 -> fp16 (single term), MFMA B-fragment order ----
__global__ void convert_w_kernel(const float* __restrict__ W1,
                                 const float* __restrict__ W2,
                                 const float* __restrict__ W3,
                                 unsigned* __restrict__ ws)
{
    int p = blockIdx.x * 256 + threadIdx.x;       // dword index (2 fp16 elems)
    if (p >= CVT_DWORDS) return;
    const int n1 = KS1 * JT1 * 256;
    const int n2 = KS2 * JT2 * 256;
    const float* W; int NK, NJ, stride, JT, oB, pl;
    if (p < n1)            { W = W1; NK = NF;  NJ = 256; stride = NF;  JT = JT1; oB = W1F/4; pl = p; }
    else if (p < n1 + n2)  { W = W2; NK = 256; NJ = 128; stride = 256; JT = JT2; oB = W2F/4; pl = p - n1; }
    else                   { W = W3; NK = 128; NJ = 22;  stride = 128; JT = JT3; oB = W3F/4; pl = p - n1 - n2; }

    const int e2   = pl & 3;
    const int lane = (pl >> 2) & 63;
    const int jt   = (pl >> 8) % JT;
    const int ks   = (pl >> 8) / JT;
    const int j    = jt * 16 + (lane & 15);
    const int kb   = ks * 32 + (lane >> 4) * 8 + e2 * 2;

    unsigned d = 0;
    #pragma unroll
    for (int q = 0; q < 2; ++q) {
        const int k = kb + q;
        const float v = (k < NK && j < NJ) ? W[j * stride + k] : 0.0f;
        d |= (unsigned)f2h(v) << (16 * q);
    }
    ws[oB + pl] = d;
}

#define MFMA16(A_, B_, C_) __builtin_amdgcn_mfma_f32_16x16x32_f16(A_, B_, C_, 0, 0, 0)

#define LOADB1(H_, KS_) { \
    _Pragma("unroll") for (int n = 0; n < 4; ++n) \
        H_[n] = *reinterpret_cast<const half8*>(&B1[((((KS_) * JT1) + (wv * 4 + n)) * 64 + lane) * 8]); }

#define COMP1(H_, KS_) { \
    half8 a_[2]; \
    _Pragma("unroll") for (int m = 0; m < 2; ++m) \
        a_[m] = *reinterpret_cast<const half8*>(&s_scr[(((KS_) * 4 + kq) * G + (m * 16 + r16)) * 8]); \
    _Pragma("unroll") for (int n = 0; n < 4; ++n) \
        _Pragma("unroll") for (int m = 0; m < 2; ++m) \
            acc[m][n] = MFMA16(a_[m], H_[n], acc[m][n]); }

#define LOADB2(H_, KS_) { \
    _Pragma("unroll") for (int n = 0; n < 2; ++n) \
        H_[n] = *reinterpret_cast<const half8*>(&B2[((((KS_) * JT2) + (wv * 2 + n)) * 64 + lane) * 8]); }

#define COMP2(H_, KS_) { \
    half8 a_[2]; \
    _Pragma("unroll") for (int m = 0; m < 2; ++m) \
        a_[m] = *reinterpret_cast<const half8*>(&s_scr[(((KS_) * 4 + kq) * G + (m * 16 + r16)) * 8]); \
    _Pragma("unroll") for (int n = 0; n < 2; ++n) \
        _Pragma("unroll") for (int m = 0; m < 2; ++m) \
            acc2[m][n] = MFMA16(a_[m], H_[n], acc2[m][n]); }

// node-major gather body (lane i -> node i, coalesced 56B/thread)
#define GATHER_BODY(I_) { \
    const int gl = batch[I_] - g0; \
    const int pp = (I_) - s_start[gl]; \
    if (pp < P) { \
        const float2* xr = reinterpret_cast<const float2*>(x + (size_t)(I_) * F); \
        _Pragma("unroll") for (int q = 0; q < 7; ++q) { \
            const float2 v = xr[q]; \
            const int k = pp * F + q * 2; \
            const unsigned d = (unsigned)f2h(v.x) | ((unsigned)f2h(v.y) << 16); \
            const int off = (((k >> 5) * 4 + ((k >> 3) & 3)) * G + gl) * 8 + (k & 7); \
            *reinterpret_cast<unsigned*>(&s_scr[off]) = d; \
        } \
    } }

#define PIN8(V_) asm volatile("" :: "v"(V_))

// ---- fused: gather -> GEMM1 -> GEMM2 -> GEMM3 ; fp16 MFMA, single-term weights ----
__global__ __launch_bounds__(256, 5)
void mlp_mfma_kernel(const float* __restrict__ x,
                     const int* __restrict__ batch,
                     const float* __restrict__ b1,
                     const float* __restrict__ b2,
                     const float* __restrict__ b3,
                     const unsigned short* __restrict__ ws,
                     float* __restrict__ out)
{
    // Activations fp16, tiled [ks][kq][graph G][e8], G=32:
    // A1 = 10240 ush @0 (k 308->320); A2 = 8192 ush @0 (h1, 256 cols);
    // A3 = 4096 ush @8192 (h2, 128 cols; overlaps only dead A1 tail).
    __shared__ __align__(16) unsigned short s_scr[12288];   // 24576 B
    __shared__ float s_b1[256], s_b2[128], s_b3[32];
    __shared__ int s_start[G + 1];

    const int t    = threadIdx.x;
    const int g0   = blockIdx.x * G;
    const int lane = t & 63;
    const int wv   = t >> 6;          // 0..3
    const int r16  = lane & 15;
    const int kq   = lane >> 4;       // 0..3

    s_b1[t] = b1[t];
    if (t < 128) s_b2[t] = b2[t];
    if (t < 32)  s_b3[t] = (t < 22) ? b3[t] : 0.0f;

    if (t <= G) {   // graph starts: windowed binary search + verified fallback
        const int target = g0 + t;
        long long wl = (long long)target * P - 5001; if (wl < 0) wl = 0;
        long long wh = (long long)target * P + 5001; if (wh > N_NODES) wh = N_NODES;
        int lo = (int)wl, hi = (int)wh;
        while (lo < hi) { int mid = (lo + hi) >> 1; if (batch[mid] < target) lo = mid + 1; else hi = mid; }
        const bool ok = (lo == 0 || batch[lo - 1] < target) &&
                        (lo == (int)N_NODES || batch[lo] >= target);
        if (!ok) {
            lo = 0; hi = (int)N_NODES;
            while (lo < hi) { int mid = (lo + hi) >> 1; if (batch[mid] < target) lo = mid + 1; else hi = mid; }
        }
        s_start[t] = lo;
    }

    for (int i = t; i < 1280; i += 256)   // pre-zero A1 (20480 B)
        reinterpret_cast<uint4*>(s_scr)[i] = make_uint4(0u, 0u, 0u, 0u);

    const unsigned short* B1 = ws + W1F / 2;
    const unsigned short* B2 = ws + W2F / 2;
    const unsigned short* B3 = ws + W3F / 2;

    half8 Ba[4], Bb[4], Bc[4];
    LOADB1(Ba, 0)                 // 3-stage prefetch; latency hides under gather
    LOADB1(Bb, 1)
    LOADB1(Bc, 2)
    __syncthreads();              // s_start + zeroed A1 visible

    // ---- gather + fp32->fp16 into tiled LDS (node-major, coalesced) ----
    // ~704 +- 27 nodes per block; unroll 4 (1024) covers mean+12sigma, tail loop exact.
    const int s0 = s_start[0], s1 = s_start[G];
    #pragma unroll
    for (int u = 0; u < 4; ++u) {
        const int i = s0 + t + u * 256;
        if (i < s1) GATHER_BODY(i)
    }
    for (int i = s0 + t + 4 * 256; i < s1; i += 256)   // tail (covers any node count)
        GATHER_BODY(i)

    // pin prefetched B1 sets: force loads to have completed-by-here, not sunk to use
    PIN8(Ba[0]); PIN8(Ba[1]); PIN8(Ba[2]); PIN8(Ba[3]);
    PIN8(Bb[0]); PIN8(Bb[1]); PIN8(Bb[2]); PIN8(Bb[3]);
    PIN8(Bc[0]); PIN8(Bc[1]); PIN8(Bc[2]); PIN8(Bc[3]);
    __syncthreads();

    // ---- GEMM1: [32 x 308] x [308 x 256]; wave owns cols [wv*64, +64); depth-3 pipeline ----
    f32x4 acc[2][4];
    #pragma unroll
    for (int m = 0; m < 2; ++m)
        #pragma unroll
        for (int n = 0; n < 4; ++n) acc[m][n] = (f32x4){0.f, 0.f, 0.f, 0.f};

    COMP1(Ba, 0)  LOADB1(Ba, 3)
    COMP1(Bb, 1)  LOADB1(Bb, 4)
    COMP1(Bc, 2)  LOADB1(Bc, 5)
    COMP1(Ba, 3)  LOADB1(Ba, 6)
    COMP1(Bb, 4)  LOADB1(Bb, 7)
    COMP1(Bc, 5)  LOADB1(Bc, 8)
    COMP1(Ba, 6)  LOADB1(Ba, 9)
    COMP1(Bb, 7)

    half8 Ca[2], Cb[2], Cc[2];
    LOADB2(Ca, 0)                 // GEMM2 stages 0-2 hide under tail of GEMM1 + epilogue 1
    LOADB2(Cb, 1)
    LOADB2(Cc, 2)
    COMP1(Bc, 8)
    COMP1(Ba, 9)
    __syncthreads();   // A1 reads done before A2 overwrite

    // epilogue 1: bias+relu -> fp16 -> A2 tiled
    #pragma unroll
    for (int n = 0; n < 4; ++n) {
        const int j = (wv * 4 + n) * 16 + r16;            // h1 col = GEMM2 k
        const float bb = s_b1[j];
        const int base = (((j >> 5) * 4 + ((j >> 3) & 3)) * G) * 8 + (j & 7);
        #pragma unroll
        for (int m = 0; m < 2; ++m)
            #pragma unroll
            for (int r = 0; r < 4; ++r) {
                const int g = m * 16 + kq * 4 + r;
                s_scr[base + g * 8] = f2h(fmaxf(acc[m][n][r] + bb, 0.0f));
            }
    }
    __syncthreads();

    // ---- GEMM2: [32 x 256] x [256 x 128]; wave owns cols [wv*32, +32); depth-3 ----
    f32x4 acc2[2][2];
    #pragma unroll
    for (int m = 0; m < 2; ++m)
        #pragma unroll
        for (int n = 0; n < 2; ++n) acc2[m][n] = (f32x4){0.f, 0.f, 0.f, 0.f};

    COMP2(Ca, 0)  LOADB2(Ca, 3)
    COMP2(Cb, 1)  LOADB2(Cb, 4)
    COMP2(Cc, 2)  LOADB2(Cc, 5)
    COMP2(Ca, 3)  LOADB2(Ca, 6)
    COMP2(Cb, 4)  LOADB2(Cb, 7)
    COMP2(Cc, 5)
    COMP2(Ca, 6)

    half8 D3[4];                  // wave's GEMM3 B (n-tile = wv&1); hides under epilogue 2
    #pragma unroll
    for (int ks = 0; ks < KS3; ++ks)
        D3[ks] = *reinterpret_cast<const half8*>(&B3[((ks * JT3 + (wv & 1)) * 64 + lane) * 8]);
    COMP2(Cb, 7)

    // epilogue 2: bias+relu -> fp16 -> A3 @8192 (disjoint from A2 [0,8192): no barrier)
    #pragma unroll
    for (int n = 0; n < 2; ++n) {
        const int j = (wv * 2 + n) * 16 + r16;            // h2 col = GEMM3 k (0..127)
        const float bb = s_b2[j];
        const int base = 8192 + (((j >> 5) * 4 + ((j >> 3) & 3)) * G) * 8 + (j & 7);
        #pragma unroll
        for (int m = 0; m < 2; ++m)
            #pragma unroll
            for (int r = 0; r < 4; ++r) {
                const int g = m * 16 + kq * 4 + r;
                s_scr[base + g * 8] = f2h(fmaxf(acc2[m][n][r] + bb, 0.0f));
            }
    }
    __syncthreads();

    // ---- GEMM3: [32 x 128] x [128 x 22(pad32)]; wave: m-tile wv>>1, n-tile wv&1 ----
    {
        f32x4 acc3 = (f32x4){0.f, 0.f, 0.f, 0.f};
        const int mg = (wv >> 1) * 16;                    // graph base of this wave's m-tile
        #pragma unroll
        for (int ks = 0; ks < KS3; ++ks) {
            const half8 a = *reinterpret_cast<const half8*>(
                &s_scr[8192 + ((ks * 4 + kq) * G + (mg + r16)) * 8]);
            acc3 = MFMA16(a, D3[ks], acc3);
        }
        const int j = (wv & 1) * 16 + r16;
        if (j < P) {
            const float bb = s_b3[j];
            #pragma unroll
            for (int r = 0; r < 4; ++r) {
                const int g = mg + kq * 4 + r;
                out[(size_t)(g0 + g) * P + j] = acc3[r] + bb;
            }
        }
    }
}

extern "C" void kernel_launch(void* const* d_in, const int* in_sizes, int n_in,
                              void* d_out, int out_size, void* d_ws, size_t ws_size,
                              hipStream_t stream) {
    const float* x     = (const float*)d_in[0];
    const int*   batch = (const int*)  d_in[1];
    const float* W1    = (const float*)d_in[2];
    const float* b1    = (const float*)d_in[3];
    const float* W2    = (const float*)d_in[4];
    const float* b2    = (const float*)d_in[5];
    const float* W3    = (const float*)d_in[6];
    const float* b3    = (const float*)d_in[7];
    float* out = (float*)d_out;

    convert_w_kernel<<<dim3((CVT_DWORDS + 255) / 256), dim3(256), 0, stream>>>(
        W1, W2, W3, (unsigned*)d_ws);
    mlp_mfma_kernel<<<dim3(NBLK), dim3(256), 0, stream>>>(
        x, batch, b1, b2, b3, (const unsigned short*)d_ws, out);
}

// Round 11
// 89.648 us; speedup vs baseline: 1.0067x; 1.0067x over previous
//
#include <hip/hip_runtime.h>
#include <hip/hip_fp16.h>

typedef __attribute__((ext_vector_type(8))) _Float16 half8;
typedef __attribute__((ext_vector_type(4))) float f32x4;

namespace {
constexpr int B_G = 131072;     // graphs
constexpr int P   = 22;
constexpr int F   = 14;
constexpr int NF  = 308;        // P*F
constexpr long long N_NODES = (long long)B_G * P;

constexpr int G    = 64;        // graphs per block
constexpr int NBLK = B_G / G;   // 2048

constexpr int KS1 = 10;         // ceil(308/32)
constexpr int KS2 = 8;          // 256/32
constexpr int KS3 = 4;          // 128/32
constexpr int JT1 = 16;         // 256/16
constexpr int JT2 = 8;          // 128/16
constexpr int JT3 = 2;          // 22 -> pad 32

// d_ws byte offsets; single-term fp16 weights, MFMA B-fragment order (1KB/fragment)
constexpr int W1F = 0;                         // 10 ks * 16KB
constexpr int W2F = W1F + KS1 * JT1 * 1024;    // 163840 ; 8 ks * 8KB
constexpr int W3F = W2F + KS2 * JT2 * 1024;    // 229376 ; 8KB
constexpr int CVT_DWORDS = (KS1*JT1 + KS2*JT2 + KS3*JT3) * 256;  // 59392

// LDS map (ush indices). A-region: A1=20480 (k 308->320), A2=16384 aliases A1 @0.
// W-region: two 16KB buffers. A3 (8192 ush) aliases WB1 after GEMM2; W3 in WB0.
constexpr int WB0 = 20480;
constexpr int WB1 = 28672;
constexpr int LDS_USH = 36864;                 // 73728 B
}

__device__ __forceinline__ unsigned short f2h(float v) {
    __half h = __float2half(v);
    return *reinterpret_cast<unsigned short*>(&h);
}

// ---- one-time weight conversion: fp32 -> fp16 (single term), MFMA B-fragment order ----
__global__ void convert_w_kernel(const float* __restrict__ W1,
                                 const float* __restrict__ W2,
                                 const float* __restrict__ W3,
                                 unsigned* __restrict__ ws)
{
    int p = blockIdx.x * 256 + threadIdx.x;       // dword index (2 fp16 elems)
    if (p >= CVT_DWORDS) return;
    const int n1 = KS1 * JT1 * 256;
    const int n2 = KS2 * JT2 * 256;
    const float* W; int NK, NJ, stride, JT, oB, pl;
    if (p < n1)            { W = W1; NK = NF;  NJ = 256; stride = NF;  JT = JT1; oB = W1F/4; pl = p; }
    else if (p < n1 + n2)  { W = W2; NK = 256; NJ = 128; stride = 256; JT = JT2; oB = W2F/4; pl = p - n1; }
    else                   { W = W3; NK = 128; NJ = 22;  stride = 128; JT = JT3; oB = W3F/4; pl = p - n1 - n2; }

    const int e2   = pl & 3;
    const int lane = (pl >> 2) & 63;
    const int jt   = (pl >> 8) % JT;
    const int ks   = (pl >> 8) / JT;
    const int j    = jt * 16 + (lane & 15);
    const int kb   = ks * 32 + (lane >> 4) * 8 + e2 * 2;

    unsigned d = 0;
    #pragma unroll
    for (int q = 0; q < 2; ++q) {
        const int k = kb + q;
        const float v = (k < NK && j < NJ) ? W[j * stride + k] : 0.0f;
        d |= (unsigned)f2h(v) << (16 * q);
    }
    ws[oB + pl] = d;
}

__device__ __forceinline__ void gload_lds16(const void* g, void* l) {
    __builtin_amdgcn_global_load_lds(
        (const __attribute__((address_space(1))) unsigned int*)g,
        (__attribute__((address_space(3))) unsigned int*)l, 16, 0, 0);
}

#define MFMA16(A_, B_, C_) __builtin_amdgcn_mfma_f32_16x16x32_f16(A_, B_, C_, 0, 0, 0)

// async stage one W1 ks-chunk (16KB, 4 rounds of 256x16B) into buffer BUF_ (ush idx)
#define STAGE_W1(KS_, BUF_) { \
    const char* gsrc = ws8 + W1F + (KS_) * 16384; \
    _Pragma("unroll") for (int r = 0; r < 4; ++r) \
        gload_lds16(gsrc + (r * 256 + t) * 16, &s_lds[(BUF_) + (r * 256 + t) * 8]); }

// async stage one W2 ks-chunk (8KB, 2 rounds)
#define STAGE_W2(KS_, BUF_) { \
    const char* gsrc = ws8 + W2F + (KS_) * 8192; \
    _Pragma("unroll") for (int r = 0; r < 2; ++r) \
        gload_lds16(gsrc + (r * 256 + t) * 16, &s_lds[(BUF_) + (r * 256 + t) * 8]); }

// async stage all of W3 (8KB, 2 rounds)
#define STAGE_W3(BUF_) { \
    const char* gsrc = ws8 + W3F; \
    _Pragma("unroll") for (int r = 0; r < 2; ++r) \
        gload_lds16(gsrc + (r * 256 + t) * 16, &s_lds[(BUF_) + (r * 256 + t) * 8]); }

// drain DMA + barrier (compiler also emits full drain before s_barrier)
#define VWBAR() { asm volatile("s_waitcnt vmcnt(0)" ::: "memory"); __syncthreads(); }

// GEMM1 step: B-fragments from LDS buffer (ds_read_b128, ~12cy) ; 16 MFMA
#define COMP1L(KS_, BUF_) { \
    half8 a_[4], b_[4]; \
    _Pragma("unroll") for (int m = 0; m < 4; ++m) \
        a_[m] = *reinterpret_cast<const half8*>(&s_lds[(((KS_) * 4 + kq) * G + (m * 16 + r16)) * 8]); \
    _Pragma("unroll") for (int n = 0; n < 4; ++n) \
        b_[n] = *reinterpret_cast<const half8*>(&s_lds[(BUF_) + (((wv * 4 + n) * 64) + lane) * 8]); \
    _Pragma("unroll") for (int n = 0; n < 4; ++n) \
        _Pragma("unroll") for (int m = 0; m < 4; ++m) \
            acc[m][n] = MFMA16(a_[m], b_[n], acc[m][n]); }

// GEMM2 step: 8 MFMA
#define COMP2L(KS_, BUF_) { \
    half8 a_[4], b_[2]; \
    _Pragma("unroll") for (int m = 0; m < 4; ++m) \
        a_[m] = *reinterpret_cast<const half8*>(&s_lds[(((KS_) * 4 + kq) * G + (m * 16 + r16)) * 8]); \
    _Pragma("unroll") for (int n = 0; n < 2; ++n) \
        b_[n] = *reinterpret_cast<const half8*>(&s_lds[(BUF_) + (((wv * 2 + n) * 64) + lane) * 8]); \
    _Pragma("unroll") for (int n = 0; n < 2; ++n) \
        _Pragma("unroll") for (int m = 0; m < 4; ++m) \
            acc2[m][n] = MFMA16(a_[m], b_[n], acc2[m][n]); }

// node-major gather body (lane i -> node i, coalesced 56B/thread)
#define GATHER_BODY(I_) { \
    const int gl = batch[I_] - g0; \
    const int pp = (I_) - s_start[gl]; \
    if (pp < P) { \
        const float2* xr = reinterpret_cast<const float2*>(x + (size_t)(I_) * F); \
        _Pragma("unroll") for (int q = 0; q < 7; ++q) { \
            const float2 v = xr[q]; \
            const int k = pp * F + q * 2; \
            const unsigned d = (unsigned)f2h(v.x) | ((unsigned)f2h(v.y) << 16); \
            const int off = (((k >> 5) * 4 + ((k >> 3) & 3)) * G + gl) * 8 + (k & 7); \
            *reinterpret_cast<unsigned*>(&s_lds[off]) = d; \
        } \
    } }

// ---- fused: gather -> GEMM1 -> GEMM2 -> GEMM3 ; W via async global_load_lds dbuf ----
__global__ __launch_bounds__(256, 2)
void mlp_mfma_kernel(const float* __restrict__ x,
                     const int* __restrict__ batch,
                     const float* __restrict__ b1,
                     const float* __restrict__ b2,
                     const float* __restrict__ b3,
                     const unsigned short* __restrict__ ws,
                     float* __restrict__ out)
{
    __shared__ __align__(16) unsigned short s_lds[LDS_USH];   // 73728 B
    __shared__ float s_b1[256], s_b2[128], s_b3[32];
    __shared__ int s_start[G + 1];

    const int t    = threadIdx.x;
    const int g0   = blockIdx.x * G;
    const int lane = t & 63;
    const int wv   = t >> 6;          // 0..3
    const int r16  = lane & 15;
    const int kq   = lane >> 4;       // 0..3
    const char* ws8 = (const char*)ws;

    s_b1[t] = b1[t];
    if (t < 128) s_b2[t] = b2[t];
    if (t < 32)  s_b3[t] = (t < 22) ? b3[t] : 0.0f;

    if (t <= G) {   // graph starts: windowed binary search + verified fallback
        const int target = g0 + t;
        long long wl = (long long)target * P - 5001; if (wl < 0) wl = 0;
        long long wh = (long long)target * P + 5001; if (wh > N_NODES) wh = N_NODES;
        int lo = (int)wl, hi = (int)wh;
        while (lo < hi) { int mid = (lo + hi) >> 1; if (batch[mid] < target) lo = mid + 1; else hi = mid; }
        const bool ok = (lo == 0 || batch[lo - 1] < target) &&
                        (lo == (int)N_NODES || batch[lo] >= target);
        if (!ok) {
            lo = 0; hi = (int)N_NODES;
            while (lo < hi) { int mid = (lo + hi) >> 1; if (batch[mid] < target) lo = mid + 1; else hi = mid; }
        }
        s_start[t] = lo;
    }

    for (int i = t; i < 2560; i += 256)   // pre-zero A1 (40960 B)
        reinterpret_cast<uint4*>(s_lds)[i] = make_uint4(0u, 0u, 0u, 0u);
    __syncthreads();              // s_start + zeroed A1 visible

    STAGE_W1(0, WB0)              // async DMA; overlaps with gather below

    // ---- gather + fp32->fp16 into tiled LDS (node-major, coalesced) ----
    const int s0 = s_start[0], s1 = s_start[G];
    #pragma unroll
    for (int u = 0; u < 7; ++u) {
        const int i = s0 + t + u * 256;
        if (i < s1) GATHER_BODY(i)
    }
    for (int i = s0 + t + 7 * 256; i < s1; i += 256)   // tail (covers any node count)
        GATHER_BODY(i)
    VWBAR()                       // A1 ready + W1 ks0 in WB0

    // ---- GEMM1: [64 x 308] x [308 x 256]; 2-phase dbuf K-loop ----
    f32x4 acc[4][4];
    #pragma unroll
    for (int m = 0; m < 4; ++m)
        #pragma unroll
        for (int n = 0; n < 4; ++n) acc[m][n] = (f32x4){0.f, 0.f, 0.f, 0.f};

    STAGE_W1(1, WB1)  COMP1L(0, WB0)  VWBAR()
    STAGE_W1(2, WB0)  COMP1L(1, WB1)  VWBAR()
    STAGE_W1(3, WB1)  COMP1L(2, WB0)  VWBAR()
    STAGE_W1(4, WB0)  COMP1L(3, WB1)  VWBAR()
    STAGE_W1(5, WB1)  COMP1L(4, WB0)  VWBAR()
    STAGE_W1(6, WB0)  COMP1L(5, WB1)  VWBAR()
    STAGE_W1(7, WB1)  COMP1L(6, WB0)  VWBAR()
    STAGE_W1(8, WB0)  COMP1L(7, WB1)  VWBAR()
    STAGE_W1(9, WB1)  COMP1L(8, WB0)  VWBAR()
    STAGE_W2(0, WB0)  COMP1L(9, WB1)  VWBAR()

    // epilogue 1: bias+relu -> fp16 -> A2 tiled (A2 aliases A1 @0; A1 dead)
    #pragma unroll
    for (int n = 0; n < 4; ++n) {
        const int j = (wv * 4 + n) * 16 + r16;            // h1 col = GEMM2 k
        const float bb = s_b1[j];
        const int base = (((j >> 5) * 4 + ((j >> 3) & 3)) * G) * 8 + (j & 7);
        #pragma unroll
        for (int m = 0; m < 4; ++m)
            #pragma unroll
            for (int r = 0; r < 4; ++r) {
                const int g = m * 16 + kq * 4 + r;
                s_lds[base + g * 8] = f2h(fmaxf(acc[m][n][r] + bb, 0.0f));
            }
    }
    __syncthreads();

    // ---- GEMM2: [64 x 256] x [256 x 128]; 2-phase dbuf ----
    f32x4 acc2[4][2];
    #pragma unroll
    for (int m = 0; m < 4; ++m)
        #pragma unroll
        for (int n = 0; n < 2; ++n) acc2[m][n] = (f32x4){0.f, 0.f, 0.f, 0.f};

    STAGE_W2(1, WB1)  COMP2L(0, WB0)  VWBAR()
    STAGE_W2(2, WB0)  COMP2L(1, WB1)  VWBAR()
    STAGE_W2(3, WB1)  COMP2L(2, WB0)  VWBAR()
    STAGE_W2(4, WB0)  COMP2L(3, WB1)  VWBAR()
    STAGE_W2(5, WB1)  COMP2L(4, WB0)  VWBAR()
    STAGE_W2(6, WB0)  COMP2L(5, WB1)  VWBAR()
    STAGE_W2(7, WB1)  COMP2L(6, WB0)  VWBAR()
    STAGE_W3(WB0)     COMP2L(7, WB1)  VWBAR()

    // epilogue 2: bias+relu -> fp16 -> A3 (aliases WB1; its readers finished at last barrier)
    #pragma unroll
    for (int n = 0; n < 2; ++n) {
        const int j = (wv * 2 + n) * 16 + r16;            // h2 col = GEMM3 k (0..127)
        const float bb = s_b2[j];
        const int base = WB1 + (((j >> 5) * 4 + ((j >> 3) & 3)) * G) * 8 + (j & 7);
        #pragma unroll
        for (int m = 0; m < 4; ++m)
            #pragma unroll
            for (int r = 0; r < 4; ++r) {
                const int g = m * 16 + kq * 4 + r;
                s_lds[base + g * 8] = f2h(fmaxf(acc2[m][n][r] + bb, 0.0f));
            }
    }
    __syncthreads();

    // ---- GEMM3: [64 x 128] x [128 x 22(pad32)]; wave wv owns graphs [wv*16,+16) ----
    {
        f32x4 acc3[2];
        acc3[0] = (f32x4){0.f, 0.f, 0.f, 0.f};
        acc3[1] = (f32x4){0.f, 0.f, 0.f, 0.f};
        #pragma unroll
        for (int ks = 0; ks < KS3; ++ks) {
            const half8 a = *reinterpret_cast<const half8*>(
                &s_lds[WB1 + ((ks * 4 + kq) * G + (wv * 16 + r16)) * 8]);
            #pragma unroll
            for (int n = 0; n < 2; ++n) {
                const half8 b = *reinterpret_cast<const half8*>(
                    &s_lds[WB0 + ((ks * JT3 + n) * 64 + lane) * 8]);
                acc3[n] = MFMA16(a, b, acc3[n]);
            }
        }
        #pragma unroll
        for (int n = 0; n < 2; ++n) {
            const int j = n * 16 + r16;
            if (j < P) {
                const float bb = s_b3[j];
                #pragma unroll
                for (int r = 0; r < 4; ++r) {
                    const int g = wv * 16 + kq * 4 + r;
                    out[(size_t)(g0 + g) * P + j] = acc3[n][r] + bb;
                }
            }
        }
    }
}

extern "C" void kernel_launch(void* const* d_in, const int* in_sizes, int n_in,
                              void* d_out, int out_size, void* d_ws, size_t ws_size,
                              hipStream_t stream) {
    const float* x     = (const float*)d_in[0];
    const int*   batch = (const int*)  d_in[1];
    const float* W1    = (const float*)d_in[2];
    const float* b1    = (const float*)d_in[3];
    const float* W2    = (const float*)d_in[4];
    const float* b2    = (const float*)d_in[5];
    const float* W3    = (const float*)d_in[6];
    const float* b3    = (const float*)d_in[7];
    float* out = (float*)d_out;

    convert_w_kernel<<<dim3((CVT_DWORDS + 255) / 256), dim3(256), 0, stream>>>(
        W1, W2, W3, (unsigned*)d_ws);
    mlp_mfma_kernel<<<dim3(NBLK), dim3(256), 0, stream>>>(
        x, batch, b1, b2, b3, (const unsigned short*)d_ws, out);
}

// Round 12
// 82.097 us; speedup vs baseline: 1.0993x; 1.0920x over previous
//
#include <hip/hip_runtime.h>
#include <hip/hip_fp16.h>

typedef __attribute__((ext_vector_type(8))) _Float16 half8;
typedef __attribute__((ext_vector_type(4))) float f32x4;

namespace {
constexpr int B_G = 131072;     // graphs
constexpr int P   = 22;
constexpr int F   = 14;
constexpr int NF  = 308;        // P*F
constexpr long long N_NODES = (long long)B_G * P;

constexpr int G    = 64;        // graphs per block
constexpr int NBLK = B_G / G;   // 2048
constexpr int NT   = 512;       // 8 waves

constexpr int KS1 = 10;         // ceil(308/32)
constexpr int KS2 = 8;          // 256/32
constexpr int KS3 = 4;          // 128/32
constexpr int JT1 = 16;         // 256/16
constexpr int JT2 = 8;          // 128/16
constexpr int JT3 = 2;          // 22 -> pad 32

// d_ws byte offsets; single-term fp16 weights, MFMA B-fragment order (1KB/fragment)
constexpr int W1F = 0;                         // 10 ks * 16KB
constexpr int W2F = W1F + KS1 * JT1 * 1024;    // 163840 ; 8 ks * 8KB
constexpr int W3F = W2F + KS2 * JT2 * 1024;    // 229376 ; 8KB
constexpr int CVT_DWORDS = (KS1*JT1 + KS2*JT2 + KS3*JT3) * 256;  // 59392

// LDS (ush idx): A1 [0,20480) (k 308->320); A2 aliases A1 [0,16384).
// WB0/WB1 = 16KB weight buffers; A3 -> WB1 after GEMM2; W3 -> WB0.
constexpr int WB0 = 20480;
constexpr int WB1 = 28672;
constexpr int LDS_USH = 36864;                 // 73728 B
}

__device__ __forceinline__ unsigned short f2h(float v) {
    __half h = __float2half(v);
    return *reinterpret_cast<unsigned short*>(&h);
}

// ---- one-time weight conversion: fp32 -> fp16, MFMA B-fragment order ----
__global__ void convert_w_kernel(const float* __restrict__ W1,
                                 const float* __restrict__ W2,
                                 const float* __restrict__ W3,
                                 unsigned* __restrict__ ws)
{
    int p = blockIdx.x * 256 + threadIdx.x;       // dword index (2 fp16 elems)
    if (p >= CVT_DWORDS) return;
    const int n1 = KS1 * JT1 * 256;
    const int n2 = KS2 * JT2 * 256;
    const float* W; int NK, NJ, stride, JT, oB, pl;
    if (p < n1)            { W = W1; NK = NF;  NJ = 256; stride = NF;  JT = JT1; oB = W1F/4; pl = p; }
    else if (p < n1 + n2)  { W = W2; NK = 256; NJ = 128; stride = 256; JT = JT2; oB = W2F/4; pl = p - n1; }
    else                   { W = W3; NK = 128; NJ = 22;  stride = 128; JT = JT3; oB = W3F/4; pl = p - n1 - n2; }

    const int e2   = pl & 3;
    const int lane = (pl >> 2) & 63;
    const int jt   = (pl >> 8) % JT;
    const int ks   = (pl >> 8) / JT;
    const int j    = jt * 16 + (lane & 15);
    const int kb   = ks * 32 + (lane >> 4) * 8 + e2 * 2;

    unsigned d = 0;
    #pragma unroll
    for (int q = 0; q < 2; ++q) {
        const int k = kb + q;
        const float v = (k < NK && j < NJ) ? W[j * stride + k] : 0.0f;
        d |= (unsigned)f2h(v) << (16 * q);
    }
    ws[oB + pl] = d;
}

__device__ __forceinline__ void gload_lds16(const void* g, void* l) {
    __builtin_amdgcn_global_load_lds(
        (const __attribute__((address_space(1))) unsigned int*)g,
        (__attribute__((address_space(3))) unsigned int*)l, 16, 0, 0);
}

#define MFMA16(A_, B_, C_) __builtin_amdgcn_mfma_f32_16x16x32_f16(A_, B_, C_, 0, 0, 0)

// counted waits (never drain in K-loop) + sched fence (rule #18 insurance)
#define WAITV(N_) { asm volatile("s_waitcnt vmcnt(" #N_ ")" ::: "memory"); __builtin_amdgcn_sched_barrier(0); }
#define WAITL()   { asm volatile("s_waitcnt lgkmcnt(0)" ::: "memory"); __builtin_amdgcn_sched_barrier(0); }
#define BAR()     __builtin_amdgcn_s_barrier()

// wave-private staging: wave w stages exactly the 2KB (W1) / 1KB (W2) it alone reads.
// dst = wave-uniform base + lane*16 (global_load_lds requirement, m104).
#define STAGE_W1(KS_, BUF_) { \
    const char* gsrc = ws8 + W1F + (KS_) * 16384 + wv * 2048; \
    gload_lds16(gsrc + lane * 16,        &s_lds[(BUF_) + (wv * 128 + lane) * 8]); \
    gload_lds16(gsrc + 1024 + lane * 16, &s_lds[(BUF_) + (wv * 128 + 64 + lane) * 8]); }

#define STAGE_W2(KS_, BUF_) { \
    const char* gsrc = ws8 + W2F + (KS_) * 8192 + wv * 1024; \
    gload_lds16(gsrc + lane * 16, &s_lds[(BUF_) + (wv * 128 + lane) * 8]); }

#define STAGE_W3(BUF_) { \
    gload_lds16(ws8 + W3F + t * 16, &s_lds[(BUF_) + t * 8]); }

// GEMM1 step: wave's 2 n-tiles from its private LDS slice; 8 MFMA
#define COMP1L(KS_, BUF_) { \
    half8 a_[4], b_[2]; \
    _Pragma("unroll") for (int m = 0; m < 4; ++m) \
        a_[m] = *reinterpret_cast<const half8*>(&s_lds[(((KS_) * 4 + kq) * G + (m * 16 + r16)) * 8]); \
    _Pragma("unroll") for (int n = 0; n < 2; ++n) \
        b_[n] = *reinterpret_cast<const half8*>(&s_lds[(BUF_) + (wv * 128 + n * 64 + lane) * 8]); \
    _Pragma("unroll") for (int n = 0; n < 2; ++n) \
        _Pragma("unroll") for (int m = 0; m < 4; ++m) \
            acc[m][n] = MFMA16(a_[m], b_[n], acc[m][n]); }

// GEMM2 step: wave's single n-tile; 4 MFMA
#define COMP2L(KS_, BUF_) { \
    half8 a_[4], b_; \
    _Pragma("unroll") for (int m = 0; m < 4; ++m) \
        a_[m] = *reinterpret_cast<const half8*>(&s_lds[(((KS_) * 4 + kq) * G + (m * 16 + r16)) * 8]); \
    b_ = *reinterpret_cast<const half8*>(&s_lds[(BUF_) + (wv * 128 + lane) * 8]); \
    _Pragma("unroll") for (int m = 0; m < 4; ++m) \
        acc2[m] = MFMA16(a_[m], b_, acc2[m]); }

// node-major gather body (lane i -> node i, coalesced 56B/thread)
#define GATHER_BODY(I_) { \
    const int gl = batch[I_] - g0; \
    const int pp = (I_) - s_start[gl]; \
    if (pp < P) { \
        const float2* xr = reinterpret_cast<const float2*>(x + (size_t)(I_) * F); \
        _Pragma("unroll") for (int q = 0; q < 7; ++q) { \
            const float2 v = xr[q]; \
            const int k = pp * F + q * 2; \
            const unsigned d = (unsigned)f2h(v.x) | ((unsigned)f2h(v.y) << 16); \
            const int off = (((k >> 5) * 4 + ((k >> 3) & 3)) * G + gl) * 8 + (k & 7); \
            *reinterpret_cast<unsigned*>(&s_lds[off]) = d; \
        } \
    } }

// ---- fused: gather -> GEMM1 -> GEMM2 -> GEMM3 ; wave-decoupled counted-vmcnt pipeline ----
__global__ __launch_bounds__(NT, 4)
void mlp_mfma_kernel(const float* __restrict__ x,
                     const int* __restrict__ batch,
                     const float* __restrict__ b1,
                     const float* __restrict__ b2,
                     const float* __restrict__ b3,
                     const unsigned short* __restrict__ ws,
                     float* __restrict__ out)
{
    __shared__ __align__(16) unsigned short s_lds[LDS_USH];   // 73728 B
    __shared__ float s_b1[256], s_b2[128], s_b3[32];
    __shared__ int s_start[G + 1];

    const int t    = threadIdx.x;
    const int g0   = blockIdx.x * G;
    const int lane = t & 63;
    const int wv   = t >> 6;          // 0..7
    const int r16  = lane & 15;
    const int kq   = lane >> 4;       // 0..3
    const char* ws8 = (const char*)ws;

    if (t < 256) s_b1[t] = b1[t];
    if (t < 128) s_b2[t] = b2[t];
    if (t < 32)  s_b3[t] = (t < 22) ? b3[t] : 0.0f;

    if (t <= G) {   // graph starts: windowed binary search + verified fallback
        const int target = g0 + t;
        long long wl = (long long)target * P - 5001; if (wl < 0) wl = 0;
        long long wh = (long long)target * P + 5001; if (wh > N_NODES) wh = N_NODES;
        int lo = (int)wl, hi = (int)wh;
        while (lo < hi) { int mid = (lo + hi) >> 1; if (batch[mid] < target) lo = mid + 1; else hi = mid; }
        const bool ok = (lo == 0 || batch[lo - 1] < target) &&
                        (lo == (int)N_NODES || batch[lo] >= target);
        if (!ok) {
            lo = 0; hi = (int)N_NODES;
            while (lo < hi) { int mid = (lo + hi) >> 1; if (batch[mid] < target) lo = mid + 1; else hi = mid; }
        }
        s_start[t] = lo;
    }

    for (int i = t; i < 2560; i += NT)   // pre-zero A1 (40960 B)
        reinterpret_cast<uint4*>(s_lds)[i] = make_uint4(0u, 0u, 0u, 0u);
    __syncthreads();              // s_start + zeroed A1 visible

    STAGE_W1(0, WB0)              // async DMA overlaps with gather
    STAGE_W1(1, WB1)

    // ---- gather + fp32->fp16 into tiled LDS (node-major, coalesced) ----
    const int s0 = s_start[0], s1 = s_start[G];
    #pragma unroll
    for (int u = 0; u < 3; ++u) {
        const int i = s0 + t + u * NT;
        if (i < s1) GATHER_BODY(i)
    }
    for (int i = s0 + t + 3 * NT; i < s1; i += NT)   // tail (covers any node count)
        GATHER_BODY(i)
    __syncthreads();              // full drain: A1 + W1 ks0/ks1 in LDS

    // ---- GEMM1: [64 x 308] x [308 x 256]; barrier-free, wave-private dbuf, counted vmcnt ----
    f32x4 acc[4][2];
    #pragma unroll
    for (int m = 0; m < 4; ++m)
        #pragma unroll
        for (int n = 0; n < 2; ++n) acc[m][n] = (f32x4){0.f, 0.f, 0.f, 0.f};

    COMP1L(0, WB0)  WAITL()  STAGE_W1(2, WB0)
    COMP1L(1, WB1)  WAITL()  STAGE_W1(3, WB1)
    WAITV(2)  COMP1L(2, WB0)  WAITL()  STAGE_W1(4, WB0)
    WAITV(2)  COMP1L(3, WB1)  WAITL()  STAGE_W1(5, WB1)
    WAITV(2)  COMP1L(4, WB0)  WAITL()  STAGE_W1(6, WB0)
    WAITV(2)  COMP1L(5, WB1)  WAITL()  STAGE_W1(7, WB1)
    WAITV(2)  COMP1L(6, WB0)  WAITL()  STAGE_W1(8, WB0)
    WAITV(2)  COMP1L(7, WB1)  WAITL()  STAGE_W1(9, WB1)
    WAITV(2)  COMP1L(8, WB0)  WAITL()  STAGE_W2(0, WB0)
    WAITV(1)  COMP1L(9, WB1)  WAITL()  STAGE_W2(1, WB1)

    BAR();   // all waves done reading A1 before A2 overwrites it

    // epilogue 1: bias+relu -> fp16 -> A2 tiled (A2 aliases A1 @0)
    #pragma unroll
    for (int n = 0; n < 2; ++n) {
        const int j = (wv * 2 + n) * 16 + r16;            // h1 col = GEMM2 k
        const float bb = s_b1[j];
        const int base = (((j >> 5) * 4 + ((j >> 3) & 3)) * G) * 8 + (j & 7);
        #pragma unroll
        for (int m = 0; m < 4; ++m)
            #pragma unroll
            for (int r = 0; r < 4; ++r) {
                const int g = m * 16 + kq * 4 + r;
                s_lds[base + g * 8] = f2h(fmaxf(acc[m][n][r] + bb, 0.0f));
            }
    }
    WAITL(); BAR();   // A2 visible to all waves

    // ---- GEMM2: [64 x 256] x [256 x 128]; barrier-free, counted vmcnt ----
    f32x4 acc2[4];
    #pragma unroll
    for (int m = 0; m < 4; ++m) acc2[m] = (f32x4){0.f, 0.f, 0.f, 0.f};

    WAITV(1)  COMP2L(0, WB0)  WAITL()  STAGE_W2(2, WB0)
    WAITV(1)  COMP2L(1, WB1)  WAITL()  STAGE_W2(3, WB1)
    WAITV(1)  COMP2L(2, WB0)  WAITL()  STAGE_W2(4, WB0)
    WAITV(1)  COMP2L(3, WB1)  WAITL()  STAGE_W2(5, WB1)
    WAITV(1)  COMP2L(4, WB0)  WAITL()  STAGE_W2(6, WB0)
    WAITV(1)  COMP2L(5, WB1)  WAITL()  STAGE_W2(7, WB1)
    WAITV(1)  COMP2L(6, WB0)  WAITL()
    WAITV(0)  COMP2L(7, WB1)  WAITL()

    BAR();            // all waves done with WB0/WB1 reads
    STAGE_W3(WB0)     // W3 (8KB) -> WB0; latency hides under epilogue 2

    // epilogue 2: bias+relu -> fp16 -> A3 in WB1
    {
        const int j = wv * 16 + r16;                      // h2 col = GEMM3 k (0..127)
        const float bb = s_b2[j];
        const int base = WB1 + (((j >> 5) * 4 + ((j >> 3) & 3)) * G) * 8 + (j & 7);
        #pragma unroll
        for (int m = 0; m < 4; ++m)
            #pragma unroll
            for (int r = 0; r < 4; ++r) {
                const int g = m * 16 + kq * 4 + r;
                s_lds[base + g * 8] = f2h(fmaxf(acc2[m][r] + bb, 0.0f));
            }
    }
    WAITL();
    WAITV(0)          // own W3 slice landed
    BAR();            // A3 + all W3 slices visible

    // ---- GEMM3: [64 x 128] x [128 x 22(pad32)]; wave: m-tile wv>>1, n-tile wv&1 ----
    {
        f32x4 acc3 = (f32x4){0.f, 0.f, 0.f, 0.f};
        const int mg = (wv >> 1) * 16;
        #pragma unroll
        for (int ks = 0; ks < KS3; ++ks) {
            const half8 a = *reinterpret_cast<const half8*>(
                &s_lds[WB1 + ((ks * 4 + kq) * G + (mg + r16)) * 8]);
            const half8 b = *reinterpret_cast<const half8*>(
                &s_lds[WB0 + ((ks * JT3 + (wv & 1)) * 64 + lane) * 8]);
            acc3 = MFMA16(a, b, acc3);
        }
        const int j = (wv & 1) * 16 + r16;
        if (j < P) {
            const float bb = s_b3[j];
            #pragma unroll
            for (int r = 0; r < 4; ++r) {
                const int g = mg + kq * 4 + r;
                out[(size_t)(g0 + g) * P + j] = acc3[r] + bb;
            }
        }
    }
}

extern "C" void kernel_launch(void* const* d_in, const int* in_sizes, int n_in,
                              void* d_out, int out_size, void* d_ws, size_t ws_size,
                              hipStream_t stream) {
    const float* x     = (const float*)d_in[0];
    const int*   batch = (const int*)  d_in[1];
    const float* W1    = (const float*)d_in[2];
    const float* b1    = (const float*)d_in[3];
    const float* W2    = (const float*)d_in[4];
    const float* b2    = (const float*)d_in[5];
    const float* W3    = (const float*)d_in[6];
    const float* b3    = (const float*)d_in[7];
    float* out = (float*)d_out;

    convert_w_kernel<<<dim3((CVT_DWORDS + 255) / 256), dim3(256), 0, stream>>>(
        W1, W2, W3, (unsigned*)d_ws);
    mlp_mfma_kernel<<<dim3(NBLK), dim3(NT), 0, stream>>>(
        x, batch, b1, b2, b3, (const unsigned short*)d_ws, out);
}

// Round 13
// 59.650 us; speedup vs baseline: 1.5130x; 1.3763x over previous
//
#include <hip/hip_runtime.h>
#include <hip/hip_fp16.h>

typedef __attribute__((ext_vector_type(8))) _Float16 half8;
typedef __attribute__((ext_vector_type(4))) float f32x4;

namespace {
constexpr int B_G = 131072;     // graphs
constexpr int P   = 22;
constexpr int F   = 14;
constexpr int NF  = 308;        // P*F
constexpr long long N_NODES = (long long)B_G * P;   // 2883584

constexpr int G    = 64;        // graphs per block
constexpr int NBLK = B_G / G;   // 2048

constexpr int KS1 = 10;         // ceil(308/32)
constexpr int KS3 = 4;          // 128/32
constexpr int JT1 = 16;         // 256/16
constexpr int JT2 = 8;          // 128/16
constexpr int JT3 = 2;          // 22 -> pad 32
constexpr int KS2 = 8;          // 256/32

// d_ws byte offsets; single-term fp16 weights, MFMA B-fragment order (1KB/fragment)
constexpr int W1F = 0;
constexpr int W2F = W1F + KS1 * JT1 * 1024;   // 163840
constexpr int W3F = W2F + KS2 * JT2 * 1024;   // 229376
constexpr int STARTS_OFF = W3F + KS3 * JT3 * 1024;  // 237568 ; (B_G+1) ints
constexpr int CVT_DWORDS = (KS1*JT1 + KS2*JT2 + KS3*JT3) * 256;  // 59392
constexpr int CVT_BLKS  = (CVT_DWORDS + 255) / 256;              // 232
constexpr int SCAN_BLKS = (int)((N_NODES + 255) / 256);          // 11264
}

__device__ __forceinline__ unsigned short f2h(float v) {
    __half h = __float2half(v);
    return *reinterpret_cast<unsigned short*>(&h);
}

// ---- aux: weight convert (blocks [0,CVT_BLKS)) + starts scan (rest) ----
__global__ void aux_kernel(const float* __restrict__ W1,
                           const float* __restrict__ W2,
                           const float* __restrict__ W3,
                           const int* __restrict__ batch,
                           unsigned* __restrict__ ws,
                           int* __restrict__ starts)
{
    const int blk = blockIdx.x;
    const int t   = threadIdx.x;
    if (blk < CVT_BLKS) {
        int p = blk * 256 + t;                    // dword index (2 fp16 elems)
        if (p >= CVT_DWORDS) return;
        const int n1 = KS1 * JT1 * 256;
        const int n2 = KS2 * JT2 * 256;
        const float* W; int NK, NJ, stride, JT, oB, pl;
        if (p < n1)            { W = W1; NK = NF;  NJ = 256; stride = NF;  JT = JT1; oB = W1F/4; pl = p; }
        else if (p < n1 + n2)  { W = W2; NK = 256; NJ = 128; stride = 256; JT = JT2; oB = W2F/4; pl = p - n1; }
        else                   { W = W3; NK = 128; NJ = 22;  stride = 128; JT = JT3; oB = W3F/4; pl = p - n1 - n2; }

        const int e2   = pl & 3;
        const int lane = (pl >> 2) & 63;
        const int jt   = (pl >> 8) % JT;
        const int ks   = (pl >> 8) / JT;
        const int j    = jt * 16 + (lane & 15);
        const int kb   = ks * 32 + (lane >> 4) * 8 + e2 * 2;

        unsigned d = 0;
        #pragma unroll
        for (int q = 0; q < 2; ++q) {
            const int k = kb + q;
            const float v = (k < NK && j < NJ) ? W[j * stride + k] : 0.0f;
            d |= (unsigned)f2h(v) << (16 * q);
        }
        ws[oB + pl] = d;
    } else {
        // starts[g] = lower_bound(batch, g): thread i writes starts for all
        // graphs transitioning at position i (batch sorted; empty graphs handled).
        const long long i = (long long)(blk - CVT_BLKS) * 256 + t;
        if (i >= N_NODES) return;
        const int b  = batch[i];
        const int bp = (i == 0) ? -1 : batch[i - 1];
        for (int g = bp + 1; g <= b; ++g) starts[g] = (int)i;
        if (i == N_NODES - 1)
            for (int g = b + 1; g <= B_G; ++g) starts[g] = (int)N_NODES;
    }
}

#define MFMA16(A_, B_, C_) __builtin_amdgcn_mfma_f32_16x16x32_f16(A_, B_, C_, 0, 0, 0)

#define LOADB1(H_, KS_) { \
    _Pragma("unroll") for (int n = 0; n < 4; ++n) \
        H_[n] = *reinterpret_cast<const half8*>(&B1[((((KS_) * JT1) + (wv * 4 + n)) * 64 + lane) * 8]); }

#define COMP1(H_, KS_) { \
    half8 a_[4]; \
    _Pragma("unroll") for (int m = 0; m < 4; ++m) \
        a_[m] = *reinterpret_cast<const half8*>(&s_scr[(((KS_) * 4 + kq) * G + (m * 16 + r16)) * 8]); \
    _Pragma("unroll") for (int n = 0; n < 4; ++n) \
        _Pragma("unroll") for (int m = 0; m < 4; ++m) \
            acc[m][n] = MFMA16(a_[m], H_[n], acc[m][n]); }

#define LOADB2(H_, KS_) { \
    _Pragma("unroll") for (int n = 0; n < 2; ++n) \
        H_[n] = *reinterpret_cast<const half8*>(&B2[((((KS_) * JT2) + (wv * 2 + n)) * 64 + lane) * 8]); }

#define COMP2(H_, KS_) { \
    half8 a_[4]; \
    _Pragma("unroll") for (int m = 0; m < 4; ++m) \
        a_[m] = *reinterpret_cast<const half8*>(&s_scr[(((KS_) * 4 + kq) * G + (m * 16 + r16)) * 8]); \
    _Pragma("unroll") for (int n = 0; n < 2; ++n) \
        _Pragma("unroll") for (int m = 0; m < 4; ++m) \
            acc2[m][n] = MFMA16(a_[m], H_[n], acc2[m][n]); }

// node-major gather body (lane i -> node i, coalesced 56B/thread)
#define GATHER_BODY(I_) { \
    const int gl = batch[I_] - g0; \
    const int pp = (I_) - s_start[gl]; \
    if (pp < P) { \
        const float2* xr = reinterpret_cast<const float2*>(x + (size_t)(I_) * F); \
        _Pragma("unroll") for (int q = 0; q < 7; ++q) { \
            const float2 v = xr[q]; \
            const int k = pp * F + q * 2; \
            const unsigned d = (unsigned)f2h(v.x) | ((unsigned)f2h(v.y) << 16); \
            const int off = (((k >> 5) * 4 + ((k >> 3) & 3)) * G + gl) * 8 + (k & 7); \
            *reinterpret_cast<unsigned*>(&s_scr[off]) = d; \
        } \
    } }

#define PIN8(V_) asm volatile("" :: "v"(V_))

// ---- fused: gather -> GEMM1 -> GEMM2 -> GEMM3 ; fp16 MFMA, single-term weights ----
__global__ __launch_bounds__(256, 3)
void mlp_mfma_kernel(const float* __restrict__ x,
                     const int* __restrict__ batch,
                     const float* __restrict__ b1,
                     const float* __restrict__ b2,
                     const float* __restrict__ b3,
                     const unsigned short* __restrict__ ws,
                     const int* __restrict__ starts,
                     float* __restrict__ out)
{
    // Activations fp16, tiled [ks][kq][graph G][e8]:
    // A1 = 20480 ush @0 (k 308->320); A2 = 16384 ush @0; A3 = 8192 ush @16384 (end 24576).
    __shared__ __align__(16) unsigned short s_scr[24576];   // 49152 B
    __shared__ float s_b1[256], s_b2[128], s_b3[32];
    __shared__ int s_start[G + 1];

    const int t    = threadIdx.x;
    const int g0   = blockIdx.x * G;
    const int lane = t & 63;
    const int wv   = t >> 6;          // 0..3
    const int r16  = lane & 15;
    const int kq   = lane >> 4;       // 0..3

    s_b1[t] = b1[t];
    if (t < 128) s_b2[t] = b2[t];
    if (t < 32)  s_b3[t] = (t < 22) ? b3[t] : 0.0f;

    if (t <= G) s_start[t] = starts[g0 + t];   // precomputed: 1 coalesced load, no search

    for (int i = t; i < 2560; i += 256)   // pre-zero A1 (40960 B)
        reinterpret_cast<uint4*>(s_scr)[i] = make_uint4(0u, 0u, 0u, 0u);

    const unsigned short* B1 = ws + W1F / 2;
    const unsigned short* B2 = ws + W2F / 2;
    const unsigned short* B3 = ws + W3F / 2;

    half8 Ba[4], Bb[4], Bc[4];
    LOADB1(Ba, 0)                 // 3-stage prefetch; latency hides under gather
    LOADB1(Bb, 1)
    LOADB1(Bc, 2)
    __syncthreads();              // s_start + zeroed A1 visible

    // ---- gather + fp32->fp16 into tiled LDS (node-major, coalesced) ----
    const int s0 = s_start[0], s1 = s_start[G];
    #pragma unroll
    for (int u = 0; u < 7; ++u) { // unrolled: ~49 independent loads in flight
        const int i = s0 + t + u * 256;
        if (i < s1) GATHER_BODY(i)
    }
    for (int i = s0 + t + 7 * 256; i < s1; i += 256)   // tail (covers any node count)
        GATHER_BODY(i)

    // pin the prefetched B1 sets (keep issued-early loads early)
    PIN8(Ba[0]); PIN8(Ba[1]); PIN8(Ba[2]); PIN8(Ba[3]);
    PIN8(Bb[0]); PIN8(Bb[1]); PIN8(Bb[2]); PIN8(Bb[3]);
    PIN8(Bc[0]); PIN8(Bc[1]); PIN8(Bc[2]); PIN8(Bc[3]);
    __syncthreads();

    // ---- GEMM1: [64 x 308] x [308 x 256]; wave owns cols [wv*64, +64); depth-3 pipeline ----
    f32x4 acc[4][4];
    #pragma unroll
    for (int m = 0; m < 4; ++m)
        #pragma unroll
        for (int n = 0; n < 4; ++n) acc[m][n] = (f32x4){0.f, 0.f, 0.f, 0.f};

    COMP1(Ba, 0)  LOADB1(Ba, 3)
    COMP1(Bb, 1)  LOADB1(Bb, 4)
    COMP1(Bc, 2)  LOADB1(Bc, 5)
    COMP1(Ba, 3)  LOADB1(Ba, 6)
    COMP1(Bb, 4)  LOADB1(Bb, 7)
    COMP1(Bc, 5)  LOADB1(Bc, 8)
    COMP1(Ba, 6)  LOADB1(Ba, 9)
    COMP1(Bb, 7)

    half8 Ca[2], Cb[2], Cc[2];
    LOADB2(Ca, 0)                 // GEMM2 stages 0-2 hide under tail of GEMM1 + epilogue 1
    LOADB2(Cb, 1)
    LOADB2(Cc, 2)
    COMP1(Bc, 8)
    COMP1(Ba, 9)
    __syncthreads();   // A1 reads done before A2 overwrite

    // epilogue 1: bias+relu -> fp16 -> A2 tiled
    #pragma unroll
    for (int n = 0; n < 4; ++n) {
        const int j = (wv * 4 + n) * 16 + r16;            // h1 col = GEMM2 k
        const float bb = s_b1[j];
        const int base = (((j >> 5) * 4 + ((j >> 3) & 3)) * G) * 8 + (j & 7);
        #pragma unroll
        for (int m = 0; m < 4; ++m)
            #pragma unroll
            for (int r = 0; r < 4; ++r) {
                const int g = m * 16 + kq * 4 + r;
                s_scr[base + g * 8] = f2h(fmaxf(acc[m][n][r] + bb, 0.0f));
            }
    }
    __syncthreads();

    // ---- GEMM2: [64 x 256] x [256 x 128]; wave owns cols [wv*32, +32); depth-3 ----
    f32x4 acc2[4][2];
    #pragma unroll
    for (int m = 0; m < 4; ++m)
        #pragma unroll
        for (int n = 0; n < 2; ++n) acc2[m][n] = (f32x4){0.f, 0.f, 0.f, 0.f};

    COMP2(Ca, 0)  LOADB2(Ca, 3)
    COMP2(Cb, 1)  LOADB2(Cb, 4)
    COMP2(Cc, 2)  LOADB2(Cc, 5)
    COMP2(Ca, 3)  LOADB2(Ca, 6)
    COMP2(Cb, 4)  LOADB2(Cb, 7)
    COMP2(Cc, 5)
    COMP2(Ca, 6)

    half8 D3[8];                  // all of GEMM3's B; hides under epilogue 2
    #pragma unroll
    for (int ks = 0; ks < KS3; ++ks)
        #pragma unroll
        for (int n = 0; n < 2; ++n)
            D3[ks * 2 + n] = *reinterpret_cast<const half8*>(&B3[((ks * JT3 + n) * 64 + lane) * 8]);
    COMP2(Cb, 7)

    // epilogue 2: bias+relu -> fp16 -> A3 @16384 (disjoint from A2: no barrier before writes)
    #pragma unroll
    for (int n = 0; n < 2; ++n) {
        const int j = (wv * 2 + n) * 16 + r16;            // h2 col = GEMM3 k (0..127)
        const float bb = s_b2[j];
        const int base = 16384 + (((j >> 5) * 4 + ((j >> 3) & 3)) * G) * 8 + (j & 7);
        #pragma unroll
        for (int m = 0; m < 4; ++m)
            #pragma unroll
            for (int r = 0; r < 4; ++r) {
                const int g = m * 16 + kq * 4 + r;
                s_scr[base + g * 8] = f2h(fmaxf(acc2[m][n][r] + bb, 0.0f));
            }
    }
    __syncthreads();

    // ---- GEMM3: [64 x 128] x [128 x 22(pad32)]; wave wv owns graphs [wv*16, +16) ----
    {
        f32x4 acc3[2];
        acc3[0] = (f32x4){0.f, 0.f, 0.f, 0.f};
        acc3[1] = (f32x4){0.f, 0.f, 0.f, 0.f};
        #pragma unroll
        for (int ks = 0; ks < KS3; ++ks) {
            const half8 a = *reinterpret_cast<const half8*>(
                &s_scr[16384 + ((ks * 4 + kq) * G + (wv * 16 + r16)) * 8]);
            #pragma unroll
            for (int n = 0; n < 2; ++n)
                acc3[n] = MFMA16(a, D3[ks * 2 + n], acc3[n]);
        }
        #pragma unroll
        for (int n = 0; n < 2; ++n) {
            const int j = n * 16 + r16;
            if (j < P) {
                const float bb = s_b3[j];
                #pragma unroll
                for (int r = 0; r < 4; ++r) {
                    const int g = wv * 16 + kq * 4 + r;
                    out[(size_t)(g0 + g) * P + j] = acc3[n][r] + bb;
                }
            }
        }
    }
}

extern "C" void kernel_launch(void* const* d_in, const int* in_sizes, int n_in,
                              void* d_out, int out_size, void* d_ws, size_t ws_size,
                              hipStream_t stream) {
    const float* x     = (const float*)d_in[0];
    const int*   batch = (const int*)  d_in[1];
    const float* W1    = (const float*)d_in[2];
    const float* b1    = (const float*)d_in[3];
    const float* W2    = (const float*)d_in[4];
    const float* b2    = (const float*)d_in[5];
    const float* W3    = (const float*)d_in[6];
    const float* b3    = (const float*)d_in[7];
    float* out = (float*)d_out;
    int* starts = (int*)((char*)d_ws + STARTS_OFF);

    aux_kernel<<<dim3(CVT_BLKS + SCAN_BLKS), dim3(256), 0, stream>>>(
        W1, W2, W3, batch, (unsigned*)d_ws, starts);
    mlp_mfma_kernel<<<dim3(NBLK), dim3(256), 0, stream>>>(
        x, batch, b1, b2, b3, (const unsigned short*)d_ws, starts, out);
}